// Round 5
// baseline (193.582 us; speedup 1.0000x reference)
//
#include <hip/hip_runtime.h>
#include <hip/hip_bf16.h>

// DIAGNOSTIC ROUND (2nd resubmit — R3/R4 hit GPUAcquisitionTimeout, never ran).
// Same gather structure as R2, but each 32-lane row-group performs the
// gather-reduce for 16 DIFFERENT rows (bijective permutation
// row_r = (grp + r*2657) & 65535), keeping only rep 0's (its own row's) sum
// for the output. Reps 1..15 are kept live via asm-volatile sinks (no DCE).
// Purpose: amplified kernel (>40 us) lands in rocprof top-5 with its own
// counter row, and K = (dur - dur_R2)/15 resolves the kernel's true cost
// vs the harness restore/poison floor. Output remains exactly correct.

#define NUM_FIELDS 26
#define REPS 16

__global__ __launch_bounds__(256) void FeaturesLinear_kernel(
    const int* __restrict__ x,        // (B, F) row-major
    const int* __restrict__ offsets,  // (F,)
    const float* __restrict__ W,      // (FEATURE_DIM, 1)
    const float* __restrict__ bias,   // (1,)
    float* __restrict__ out,          // (B, 1)
    int batch) {
  const int l = threadIdx.x & 31;                                // lane in row-group
  const int grp = (blockIdx.x * blockDim.x + threadIdx.x) >> 5;  // this group's own row
  if (grp >= batch) return;

  const int lc = (l < NUM_FIELDS) ? l : (NUM_FIELDS - 1);
  const int off = offsets[lc];

  float s0 = 0.f;
#pragma unroll
  for (int r = 0; r < REPS; ++r) {
    const int row = (grp + r * 2657) & (batch - 1);  // bijective per-rep row permutation
    const int idx = x[row * NUM_FIELDS + lc] + off;
    float v = W[idx];
    if (l >= NUM_FIELDS) v = 0.f;
    if (r == 0) {
      s0 = v;                          // the real result (own row)
    } else {
      asm volatile("" ::"v"(v));       // keep rep live; prevent DCE (rule #17)
    }
  }

  // Reduce rep-0 value across the 32-lane group.
  float v = s0;
#pragma unroll
  for (int m = 16; m > 0; m >>= 1) v += __shfl_xor(v, m, 32);

  if (l == 0) out[grp] = v + bias[0];
}

extern "C" void kernel_launch(void* const* d_in, const int* in_sizes, int n_in,
                              void* d_out, int out_size, void* d_ws, size_t ws_size,
                              hipStream_t stream) {
  const int* x = (const int*)d_in[0];
  const int* offsets = (const int*)d_in[1];
  const float* W = (const float*)d_in[2];
  const float* bias = (const float*)d_in[3];
  float* out = (float*)d_out;

  int batch = in_sizes[0] / NUM_FIELDS;  // 65536

  const int block = 256;  // 8 row-groups per block
  const int rows_per_block = block / 32;
  dim3 grid((batch + rows_per_block - 1) / rows_per_block);
  FeaturesLinear_kernel<<<grid, dim3(block), 0, stream>>>(x, offsets, W, bias, out, batch);
}

// Round 6
// 74.893 us; speedup vs baseline: 2.5848x; 2.5848x over previous
//
#include <hip/hip_runtime.h>
#include <hip/hip_bf16.h>

// FeaturesLinear: out[b] = sum_f W[x[b,f] + offsets[f]] + bias
// R6: ILP-4 gather. Each 32-lane group handles 4 rows (lane l = field l,
// 4 independent W-gathers in flight per thread). x staged via LDS with
// fully coalesced block loads. Grid 2048 blocks -> 8 blocks/CU -> 32
// waves/CU AND ILP 4: reproduces the R5-amplified steady-state regime
// (8.5 us/rep transaction floor) without the 16x x-traffic.

#define NUM_FIELDS 26
#define ROWS_PER_GROUP 4
#define BLOCK 256
#define GROUPS_PER_BLOCK (BLOCK / 32)                       // 8
#define ROWS_PER_BLOCK (GROUPS_PER_BLOCK * ROWS_PER_GROUP)  // 32
#define INTS_PER_BLOCK (ROWS_PER_BLOCK * NUM_FIELDS)        // 832

__global__ __launch_bounds__(256) void FeaturesLinear_kernel(
    const int* __restrict__ x,        // (B, F) row-major
    const int* __restrict__ offsets,  // (F,)
    const float* __restrict__ W,      // (FEATURE_DIM, 1)
    const float* __restrict__ bias,   // (1,)
    float* __restrict__ out,          // (B, 1)
    int batch) {
  __shared__ int xs[INTS_PER_BLOCK];

  const int tid = threadIdx.x;
  const int block_row0 = blockIdx.x * ROWS_PER_BLOCK;
  const int* xb = x + block_row0 * NUM_FIELDS;

  // Coalesced stage of 32 rows (832 ints) into LDS.
#pragma unroll
  for (int i = 0; i < (INTS_PER_BLOCK + BLOCK - 1) / BLOCK; ++i) {
    int o = tid + i * BLOCK;
    if (o < INTS_PER_BLOCK) xs[o] = xb[o];
  }
  __syncthreads();

  const int l = tid & 31;   // lane in group = field
  const int g = tid >> 5;   // group -> 4 rows
  const int lc = (l < NUM_FIELDS) ? l : (NUM_FIELDS - 1);
  const int off = offsets[lc];

  // 4 independent gathers (ILP) per thread.
  int idx[ROWS_PER_GROUP];
#pragma unroll
  for (int r = 0; r < ROWS_PER_GROUP; ++r) {
    idx[r] = xs[(g * ROWS_PER_GROUP + r) * NUM_FIELDS + lc] + off;
  }
  float v[ROWS_PER_GROUP];
#pragma unroll
  for (int r = 0; r < ROWS_PER_GROUP; ++r) {
    float t = W[idx[r]];
    v[r] = (l < NUM_FIELDS) ? t : 0.f;
  }

  // Reduce each row-sum across the 32-lane group (4 independent trees).
#pragma unroll
  for (int m = 16; m > 0; m >>= 1) {
#pragma unroll
    for (int r = 0; r < ROWS_PER_GROUP; ++r) v[r] += __shfl_xor(v[r], m, 32);
  }

  // Lanes 0..3 write rows r=lane. Static-index selection (no runtime array
  // indexing -> stays in registers, rule #20).
  if (l < ROWS_PER_GROUP) {
    float wv = (l == 0) ? v[0] : (l == 1) ? v[1] : (l == 2) ? v[2] : v[3];
    out[block_row0 + g * ROWS_PER_GROUP + l] = wv + bias[0];
  }
}

extern "C" void kernel_launch(void* const* d_in, const int* in_sizes, int n_in,
                              void* d_out, int out_size, void* d_ws, size_t ws_size,
                              hipStream_t stream) {
  const int* x = (const int*)d_in[0];
  const int* offsets = (const int*)d_in[1];
  const float* W = (const float*)d_in[2];
  const float* bias = (const float*)d_in[3];
  float* out = (float*)d_out;

  int batch = in_sizes[0] / NUM_FIELDS;  // 65536

  dim3 grid(batch / ROWS_PER_BLOCK);  // 2048
  FeaturesLinear_kernel<<<grid, dim3(BLOCK), 0, stream>>>(x, offsets, W, bias, out, batch);
}